// Round 5
// baseline (358046.069 us; speedup 1.0000x reference)
//
#include <hip/hip_runtime.h>
#include <hip/hip_bf16.h>
#include <stdint.h>

#define SEQ     8192
#define DIM     2048
#define HID     1024
#define NWG     256
#define CPW     8      // output columns per workgroup

typedef unsigned long long u64;
typedef __attribute__((ext_vector_type(4))) unsigned int u32x4;

// ---- workspace layout (bytes) ----
//   0     : flags8[256] (u8)  -- per-WG phase flag, value (5t+l+1) & 0xFF
//   4096  : H[1024]    (f32)  -- hidden state (written as u64 pairs)
//   8192  : actA[2048] (f32)  -- layer act ping (layers 0,2 write; 1,3 read)
//   16384 : actB[2048] (f32)  -- layer act pong (layers 1,3 write; 2,4 read)
//   memset first 24576 B per call: flags=0, H=0 ("ready for t=0")

__device__ __forceinline__ uint16_t f2bf(float f) {
  union { float f; uint32_t u; } v; v.f = f;
  uint32_t r = v.u + 0x7FFFu + ((v.u >> 16) & 1u);   // round-to-nearest-even
  return (uint16_t)(r >> 16);
}
__device__ __forceinline__ float bf2f(uint16_t u) {
  union { uint32_t u; float f; } v; v.u = ((uint32_t)u) << 16; return v.f;
}

// agent-scope relaxed atomics -> global ops with sc0 sc1: coherent at L3,
// bypass the non-coherent per-XCD L2. No fences needed anywhere.
__device__ __forceinline__ void cstore8(uint8_t* p, uint8_t v) {
  __hip_atomic_store(p, v, __ATOMIC_RELAXED, __HIP_MEMORY_SCOPE_AGENT);
}
__device__ __forceinline__ void cstore64(u64* p, u64 v) {
  __hip_atomic_store(p, v, __ATOMIC_RELAXED, __HIP_MEMORY_SCOPE_AGENT);
}
__device__ __forceinline__ u64 packf2(float a, float b) {
  union { float2 f; u64 u; } c; c.f.x = a; c.f.y = b; return c.u;
}

// 16B coherent load (4 dwords, one request). Result NOT valid until a
// following s_waitcnt vmcnt(0) + sched_barrier(0) (rule #18).
__device__ __forceinline__ u32x4 cload128(const void* p) {
  u32x4 r;
  asm volatile("global_load_dwordx4 %0, %1, off sc0 sc1"
               : "=v"(r) : "v"(p) : "memory");
  return r;
}
__device__ __forceinline__ void vm_drain() {
  asm volatile("s_waitcnt vmcnt(0)" ::: "memory");
  __builtin_amdgcn_sched_barrier(0);
}

// Poll one 64B line of 16*4 u8 flags (4 lanes x dwordx4) until all >= tgt
// (wraparound-safe: producer/consumer skew is <=2 phases << 128).
__device__ __forceinline__ void poll_line(const uint8_t* line, int lane,
                                          uint8_t tgt) {
  for (;;) {
    bool ok = true;
    if (lane < 4) {
      u32x4 q = cload128(line + lane * 16);
      vm_drain();
      #pragma unroll
      for (int d = 0; d < 4; ++d) {
        const uint32_t w = q[d];
        #pragma unroll
        for (int b = 0; b < 4; ++b)
          ok &= (uint8_t)((uint8_t)(w >> (8 * b)) - tgt) < 128u;
      }
    }
    if (__all(ok)) return;
    __builtin_amdgcn_s_sleep(1);
  }
}

__global__ void __launch_bounds__(256, 1)
rnn_persist(const float* __restrict__ x, const float* __restrict__ W0,
            const float* __restrict__ b0, const float* __restrict__ Wmid,
            const float* __restrict__ bmid, const float* __restrict__ Wf,
            const float* __restrict__ bfv, float* __restrict__ out,
            uint8_t* __restrict__ flags8, float* __restrict__ Hbuf,
            float* __restrict__ actA, float* __restrict__ actB)
{
  __shared__ uint16_t wlds[4 * CPW * DIM];   // layers 0-3 weights, 128 KiB
  __shared__ float    sAct[DIM];             // staged activation vector, 8 KiB

  const int tid  = threadIdx.x;
  const int wg   = blockIdx.x;
  const int wave = tid >> 6;
  const int lane = tid & 63;

  // each wave owns 2 adjacent output columns of every layer
  const int cidx0 = wave * 2;
  const int col0  = wg * CPW + cidx0;
  const int col1  = col0 + 1;

  // ---- stage layers 0-3 weight slice (bf16) into LDS, once ----
  for (int i = tid; i < 4 * CPW * DIM; i += 256) {
    const int l = i >> 14;           // / (CPW*DIM)
    const int r = i & 16383;
    const int k = r >> 3;            // 0..2047
    const int c = r & 7;             // 0..7
    const float* Ws = (l == 0) ? W0 : (Wmid + (size_t)(l - 1) * DIM * DIM);
    wlds[(l * CPW + c) * DIM + k] = f2bf(Ws[(size_t)k * DIM + (wg * CPW + c)]);
  }
  // ---- layer-4 weights into registers: 2 cols x 32 k-vals/lane ----
  ushort4 wf0[8], wf1[8];
  #pragma unroll
  for (int j = 0; j < 8; ++j) {
    const int k = j * 256 + lane * 4;
    wf0[j].x = f2bf(Wf[(size_t)(k + 0) * DIM + col0]);
    wf0[j].y = f2bf(Wf[(size_t)(k + 1) * DIM + col0]);
    wf0[j].z = f2bf(Wf[(size_t)(k + 2) * DIM + col0]);
    wf0[j].w = f2bf(Wf[(size_t)(k + 3) * DIM + col0]);
    wf1[j].x = f2bf(Wf[(size_t)(k + 0) * DIM + col1]);
    wf1[j].y = f2bf(Wf[(size_t)(k + 1) * DIM + col1]);
    wf1[j].z = f2bf(Wf[(size_t)(k + 2) * DIM + col1]);
    wf1[j].w = f2bf(Wf[(size_t)(k + 3) * DIM + col1]);
  }
  __syncthreads();

  float bias0[5], bias1[5];
  bias0[0] = b0[col0];              bias1[0] = b0[col1];
  bias0[1] = bmid[0 * DIM + col0];  bias1[1] = bmid[0 * DIM + col1];
  bias0[2] = bmid[1 * DIM + col0];  bias1[2] = bmid[1 * DIM + col1];
  bias0[3] = bmid[2 * DIM + col0];  bias1[3] = bmid[2 * DIM + col1];
  bias0[4] = bfv[col0];             bias1[4] = bfv[col1];

  const bool hWG = (wg < 128);   // layer-4 columns of this WG are H (else outputs)

  for (int t = 0; t < SEQ; ++t) {
    const float* __restrict__ xrow = x + (size_t)t * HID;

    #pragma unroll
    for (int l = 0; l < 5; ++l) {
      // ================= acquire + stage this wave's quarter =================
      if (l == 0) {
        if (wave < 2) {
          // x half: plain cached loads, no dependency
          const int f0 = wave * 512 + lane * 8;
          const float4 a0 = *(const float4*)(xrow + f0);
          const float4 a1 = *(const float4*)(xrow + f0 + 4);
          *(float4*)&sAct[f0]     = a0;
          *(float4*)&sAct[f0 + 4] = a1;
        } else {
          // H half: poll this half's 64 H-producer flags (one 64B line)
          const int hq = wave - 2;                       // 0 or 1
          poll_line(flags8 + hq * 64, lane, (uint8_t)(5u * (uint32_t)t));
          const float* hp = Hbuf + hq * 512 + lane * 8;
          const u32x4 p0 = cload128(hp);
          const u32x4 p1 = cload128(hp + 4);
          vm_drain();
          const int f0 = 1024 + hq * 512 + lane * 8;
          #pragma unroll
          for (int m = 0; m < 4; ++m) {                  // hidden: no relu
            sAct[f0 + m]     = __uint_as_float(p0[m]);
            sAct[f0 + 4 + m] = __uint_as_float(p1[m]);
          }
        }
      } else {
        const float* __restrict__ src = (l & 1) ? actA : actB;
        poll_line(flags8 + wave * 64, lane,
                  (uint8_t)(5u * (uint32_t)t + (uint32_t)l));
        const float* sp = src + wave * 512 + lane * 8;
        const u32x4 p0 = cload128(sp);
        const u32x4 p1 = cload128(sp + 4);
        vm_drain();
        const int f0 = wave * 512 + lane * 8;
        #pragma unroll
        for (int m = 0; m < 4; ++m) {                    // relu at stage time
          sAct[f0 + m]     = fmaxf(__uint_as_float(p0[m]), 0.f);
          sAct[f0 + 4 + m] = fmaxf(__uint_as_float(p1[m]), 0.f);
        }
      }
      __syncthreads();   // staging complete -> full vector visible to all waves

      // ========================== dot products ==========================
      float acc0 = 0.f, acc1 = 0.f;
      if (l < 4) {
        const uint16_t* w0p = wlds + ((l * CPW + cidx0) * DIM);
        const uint16_t* w1p = w0p + DIM;
        #pragma unroll
        for (int j = 0; j < 8; ++j) {
          const int kb = j * 256 + lane * 4;
          const float4  a  = *(const float4*)&sAct[kb];
          const ushort4 wa = *(const ushort4*)(w0p + kb);
          const ushort4 wb = *(const ushort4*)(w1p + kb);
          acc0 = fmaf(a.x, bf2f(wa.x), acc0); acc1 = fmaf(a.x, bf2f(wb.x), acc1);
          acc0 = fmaf(a.y, bf2f(wa.y), acc0); acc1 = fmaf(a.y, bf2f(wb.y), acc1);
          acc0 = fmaf(a.z, bf2f(wa.z), acc0); acc1 = fmaf(a.z, bf2f(wb.z), acc1);
          acc0 = fmaf(a.w, bf2f(wa.w), acc0); acc1 = fmaf(a.w, bf2f(wb.w), acc1);
        }
      } else {
        #pragma unroll
        for (int j = 0; j < 8; ++j) {
          const int kb = j * 256 + lane * 4;
          const float4  a  = *(const float4*)&sAct[kb];
          const ushort4 wa = wf0[j];
          const ushort4 wb = wf1[j];
          acc0 = fmaf(a.x, bf2f(wa.x), acc0); acc1 = fmaf(a.x, bf2f(wb.x), acc1);
          acc0 = fmaf(a.y, bf2f(wa.y), acc0); acc1 = fmaf(a.y, bf2f(wb.y), acc1);
          acc0 = fmaf(a.z, bf2f(wa.z), acc0); acc1 = fmaf(a.z, bf2f(wb.z), acc1);
          acc0 = fmaf(a.w, bf2f(wa.w), acc0); acc1 = fmaf(a.w, bf2f(wb.w), acc1);
        }
      }
      #pragma unroll
      for (int off = 32; off > 0; off >>= 1) {
        acc0 += __shfl_xor(acc0, off, 64);
        acc1 += __shfl_xor(acc1, off, 64);
      }

      // ========================== publish ==========================
      const bool finalStep = (t == SEQ - 1);
      const bool producer  = (l < 4) || (hWG && !finalStep);

      if (lane == 0) {
        const float v0 = acc0 + bias0[l];
        const float v1 = acc1 + bias1[l];
        if (l < 4) {
          u64* dst = (u64*)((l & 1) ? actB : actA);
          cstore64(dst + (col0 >> 1), packf2(v0, v1));
        } else if (hWG) {
          if (!finalStep) {
            cstore64((u64*)Hbuf + (col0 >> 1), packf2(v0, v1));
          } else {
            float2 o; o.x = v0; o.y = v1;
            *(float2*)(out + col0) = o;                          // final hidden
          }
        } else {
          float2 o; o.x = v0; o.y = v1;
          *(float2*)(out + HID + (size_t)t * HID + (col0 - HID)) = o;  // outputs[t]
        }
      }
      if (producer)
        asm volatile("s_waitcnt vmcnt(0)" ::: "memory");  // data at L3 pre-flag
      __syncthreads();                                    // all 4 waves done
      if (tid == 0 && producer)
        cstore8(flags8 + wg, (uint8_t)(5u * (uint32_t)t + (uint32_t)l + 1u));
    }
  }
}

extern "C" void kernel_launch(void* const* d_in, const int* in_sizes, int n_in,
                              void* d_out, int out_size, void* d_ws, size_t ws_size,
                              hipStream_t stream) {
  (void)in_sizes; (void)n_in; (void)out_size; (void)ws_size;
  const float* x    = (const float*)d_in[0];
  const float* W0   = (const float*)d_in[1];
  const float* b0   = (const float*)d_in[2];
  const float* Wmid = (const float*)d_in[3];
  const float* bmid = (const float*)d_in[4];
  const float* Wf   = (const float*)d_in[5];
  const float* bfv  = (const float*)d_in[6];
  float* out = (float*)d_out;

  uint8_t* ws = (uint8_t*)d_ws;
  uint8_t*  flags8 = (uint8_t*)(ws + 0);
  float*    Hbuf   = (float*)(ws + 4096);
  float*    actA   = (float*)(ws + 8192);
  float*    actB   = (float*)(ws + 16384);

  // reset flags + hidden state every call (graph-replay safe)
  hipMemsetAsync(d_ws, 0, 24576, stream);

  rnn_persist<<<dim3(NWG), dim3(256), 0, stream>>>(
      x, W0, b0, Wmid, bmid, Wf, bfv, out, flags8, Hbuf, actA, actB);
}

// Round 6
// 180031.860 us; speedup vs baseline: 1.9888x; 1.9888x over previous
//
#include <hip/hip_runtime.h>
#include <hip/hip_bf16.h>
#include <stdint.h>

#define SEQ     8192
#define DIM     2048
#define HID     1024
#define NWG     256
#define CPW     8      // output columns per workgroup

typedef unsigned long long u64;
typedef __attribute__((ext_vector_type(4))) unsigned int u32x4;

// ---- workspace layout (bytes) ----
//   0     : Hbuf[1024] (u32 {bf16 val | u16 tag}) -- hidden, tag = t+1 when written
//   4096  : bufA[2048] (u32 tagged)  -- layers 0,2 write; 1,3 read
//   12288 : bufB[2048] (u32 tagged)  -- layers 1,3 write; 2,4 read
//   memset first 20480 B per call: val=0bf16, tag=0 == "H ready for t=0"
//
// Tags: layer-l output of step t carries tag 4t+l+1 (l=0..3); H carries t+1.
// Max tag 4*8191+4 = 32768 < 2^16 -> no wraparound ever. Poll uses wrap-safe
// (u16)(tag - tgt) < 0x8000 anyway.
//
// Safety (no flags, no producer fence): value+tag share one u32 (un-torn);
// a consumer observing tag p implies the producer's store committed at the
// coherence point, which implies (data-dependence) the producer finished
// READING its own inputs. Each WG's 4 waves jointly poll all 256 producers
// every phase, joined by the per-phase __syncthreads, so any store at phase
// p+2 transitively happens-after every read of phase p's buffer (ping-pong
// period 2). sAct is double-buffered so one barrier per phase suffices.

__device__ __forceinline__ uint16_t f2bf(float f) {
  union { float f; uint32_t u; } v; v.f = f;
  uint32_t r = v.u + 0x7FFFu + ((v.u >> 16) & 1u);   // round-to-nearest-even
  return (uint16_t)(r >> 16);
}
__device__ __forceinline__ float bf2f(uint16_t u) {
  union { uint32_t u; float f; } v; v.u = ((uint32_t)u) << 16; return v.f;
}

__device__ __forceinline__ void cstore64(u64* p, u64 v) {
  __hip_atomic_store(p, v, __ATOMIC_RELAXED, __HIP_MEMORY_SCOPE_AGENT);
}
// pack two tagged bf16 values (adjacent columns) into one 8B store
__device__ __forceinline__ u64 pack2(float v0, float v1, uint32_t tag) {
  const uint32_t w0 = (uint32_t)f2bf(v0) | (tag << 16);
  const uint32_t w1 = (uint32_t)f2bf(v1) | (tag << 16);
  return ((u64)w1 << 32) | (u64)w0;
}

// 16B coherent load (sc0 sc1 -> serviced at the coherent L3/MALL, bypasses
// the non-coherent per-XCD L2). Result valid only after vm_drain (rule #18).
__device__ __forceinline__ u32x4 cload128(const void* p) {
  u32x4 r;
  asm volatile("global_load_dwordx4 %0, %1, off sc0 sc1"
               : "=v"(r) : "v"(p) : "memory");
  return r;
}
__device__ __forceinline__ void vm_drain() {
  asm volatile("s_waitcnt vmcnt(0)" ::: "memory");
  __builtin_amdgcn_sched_barrier(0);
}

// Poll this lane's 8 tagged u32 (32B, 2 requests) of a 512-col quarter until
// every tag >= tgt; then decode straight into the LDS staging buffer.
__device__ __forceinline__ void poll_stage(const uint32_t* __restrict__ qbase,
                                           int lane, uint16_t tgt, bool relu,
                                           float* __restrict__ sdst) {
  const uint32_t* p = qbase + lane * 8;
  u32x4 a, b;
  for (;;) {
    a = cload128(p);
    b = cload128(p + 4);
    vm_drain();
    bool ok = true;
    #pragma unroll
    for (int i = 0; i < 4; ++i) {
      ok &= (uint16_t)((uint16_t)(a[i] >> 16) - tgt) < 0x8000u;
      ok &= (uint16_t)((uint16_t)(b[i] >> 16) - tgt) < 0x8000u;
    }
    if (__all(ok)) break;
    __builtin_amdgcn_s_sleep(1);
  }
  float* d = sdst + lane * 8;
  #pragma unroll
  for (int i = 0; i < 4; ++i) {
    float fa = __uint_as_float(a[i] << 16);     // bf16 -> f32
    float fb = __uint_as_float(b[i] << 16);
    if (relu) { fa = fmaxf(fa, 0.f); fb = fmaxf(fb, 0.f); }
    d[i]     = fa;
    d[4 + i] = fb;
  }
}

__global__ void __launch_bounds__(256, 1)
rnn_persist(const float* __restrict__ x, const float* __restrict__ W0,
            const float* __restrict__ b0, const float* __restrict__ Wmid,
            const float* __restrict__ bmid, const float* __restrict__ Wf,
            const float* __restrict__ bfv, float* __restrict__ out,
            uint32_t* __restrict__ Hbuf, uint32_t* __restrict__ bufA,
            uint32_t* __restrict__ bufB)
{
  __shared__ uint16_t wlds[4 * CPW * DIM];   // layers 0-3 weights, 128 KiB
  __shared__ float    sAct[2][DIM];          // double-buffered staged acts, 16 KiB

  const int tid  = threadIdx.x;
  const int wg   = blockIdx.x;
  const int wave = tid >> 6;
  const int lane = tid & 63;

  // each wave owns 2 adjacent output columns of every layer
  const int cidx0 = wave * 2;
  const int col0  = wg * CPW + cidx0;
  const int col1  = col0 + 1;

  // ---- stage layers 0-3 weight slice (bf16) into LDS, once ----
  for (int i = tid; i < 4 * CPW * DIM; i += 256) {
    const int l = i >> 14;           // / (CPW*DIM)
    const int r = i & 16383;
    const int k = r >> 3;            // 0..2047
    const int c = r & 7;             // 0..7
    const float* Ws = (l == 0) ? W0 : (Wmid + (size_t)(l - 1) * DIM * DIM);
    wlds[(l * CPW + c) * DIM + k] = f2bf(Ws[(size_t)k * DIM + (wg * CPW + c)]);
  }
  // ---- layer-4 weights into registers: 2 cols x 32 k-vals/lane ----
  ushort4 wf0[8], wf1[8];
  #pragma unroll
  for (int j = 0; j < 8; ++j) {
    const int k = j * 256 + lane * 4;
    wf0[j].x = f2bf(Wf[(size_t)(k + 0) * DIM + col0]);
    wf0[j].y = f2bf(Wf[(size_t)(k + 1) * DIM + col0]);
    wf0[j].z = f2bf(Wf[(size_t)(k + 2) * DIM + col0]);
    wf0[j].w = f2bf(Wf[(size_t)(k + 3) * DIM + col0]);
    wf1[j].x = f2bf(Wf[(size_t)(k + 0) * DIM + col1]);
    wf1[j].y = f2bf(Wf[(size_t)(k + 1) * DIM + col1]);
    wf1[j].z = f2bf(Wf[(size_t)(k + 2) * DIM + col1]);
    wf1[j].w = f2bf(Wf[(size_t)(k + 3) * DIM + col1]);
  }
  __syncthreads();

  float bias0[5], bias1[5];
  bias0[0] = b0[col0];              bias1[0] = b0[col1];
  bias0[1] = bmid[0 * DIM + col0];  bias1[1] = bmid[0 * DIM + col1];
  bias0[2] = bmid[1 * DIM + col0];  bias1[2] = bmid[1 * DIM + col1];
  bias0[3] = bmid[2 * DIM + col0];  bias1[3] = bmid[2 * DIM + col1];
  bias0[4] = bfv[col0];             bias1[4] = bfv[col1];

  const bool hWG = (wg < 128);   // layer-4 columns of this WG are H (else outputs)

  int par = 0;   // phase parity for sAct double buffer

  for (int t = 0; t < SEQ; ++t) {
    const float* __restrict__ xrow = x + (size_t)t * HID;

    #pragma unroll
    for (int l = 0; l < 5; ++l) {
      float* __restrict__ sa = sAct[par];

      // ============ acquire + stage this wave's quarter into sAct ============
      if (l == 0) {
        if (wave < 2) {
          // x half: plain cached loads (overlaps other waves' H poll)
          const int f0 = wave * 512 + lane * 8;
          const float4 a0 = *(const float4*)(xrow + f0);
          const float4 a1 = *(const float4*)(xrow + f0 + 4);
          *(float4*)&sa[f0]     = a0;
          *(float4*)&sa[f0 + 4] = a1;
        } else {
          const int hq = wave - 2;   // H halves: no relu
          poll_stage(Hbuf + hq * 512, lane, (uint16_t)t, false,
                     sa + 1024 + hq * 512);
        }
      } else {
        const uint32_t* __restrict__ src = (l & 1) ? bufA : bufB;
        poll_stage(src + wave * 512, lane,
                   (uint16_t)(4u * (uint32_t)t + (uint32_t)l), true,
                   sa + wave * 512);
      }
      __syncthreads();   // full vector staged; also the transitive-safety join

      // ========================== dot products ==========================
      float acc0 = 0.f, acc1 = 0.f;
      if (l < 4) {
        const uint16_t* w0p = wlds + ((l * CPW + cidx0) * DIM);
        const uint16_t* w1p = w0p + DIM;
        #pragma unroll
        for (int j = 0; j < 8; ++j) {
          const int kb = j * 256 + lane * 4;
          const float4  a  = *(const float4*)&sa[kb];
          const ushort4 wa = *(const ushort4*)(w0p + kb);
          const ushort4 wb = *(const ushort4*)(w1p + kb);
          acc0 = fmaf(a.x, bf2f(wa.x), acc0); acc1 = fmaf(a.x, bf2f(wb.x), acc1);
          acc0 = fmaf(a.y, bf2f(wa.y), acc0); acc1 = fmaf(a.y, bf2f(wb.y), acc1);
          acc0 = fmaf(a.z, bf2f(wa.z), acc0); acc1 = fmaf(a.z, bf2f(wb.z), acc1);
          acc0 = fmaf(a.w, bf2f(wa.w), acc0); acc1 = fmaf(a.w, bf2f(wb.w), acc1);
        }
      } else {
        #pragma unroll
        for (int j = 0; j < 8; ++j) {
          const int kb = j * 256 + lane * 4;
          const float4  a  = *(const float4*)&sa[kb];
          const ushort4 wa = wf0[j];
          const ushort4 wb = wf1[j];
          acc0 = fmaf(a.x, bf2f(wa.x), acc0); acc1 = fmaf(a.x, bf2f(wb.x), acc1);
          acc0 = fmaf(a.y, bf2f(wa.y), acc0); acc1 = fmaf(a.y, bf2f(wb.y), acc1);
          acc0 = fmaf(a.z, bf2f(wa.z), acc0); acc1 = fmaf(a.z, bf2f(wb.z), acc1);
          acc0 = fmaf(a.w, bf2f(wa.w), acc0); acc1 = fmaf(a.w, bf2f(wb.w), acc1);
        }
      }
      #pragma unroll
      for (int off = 32; off > 0; off >>= 1) {
        acc0 += __shfl_xor(acc0, off, 64);
        acc1 += __shfl_xor(acc1, off, 64);
      }

      // ============ publish: tagged 8B store, fire-and-continue ============
      if (lane == 0) {
        const float v0 = acc0 + bias0[l];
        const float v1 = acc1 + bias1[l];
        if (l < 4) {
          uint32_t* dst = (l & 1) ? bufB : bufA;
          cstore64((u64*)dst + (col0 >> 1),
                   pack2(v0, v1, 4u * (uint32_t)t + (uint32_t)l + 1u));
        } else if (hWG) {
          if (t < SEQ - 1) {
            cstore64((u64*)Hbuf + (col0 >> 1), pack2(v0, v1, (uint32_t)t + 1u));
          } else {
            float2 o; o.x = v0; o.y = v1;
            *(float2*)(out + col0) = o;                          // final hidden
          }
        } else {
          float2 o; o.x = v0; o.y = v1;
          *(float2*)(out + HID + (size_t)t * HID + (col0 - HID)) = o;  // outputs[t]
        }
      }
      par ^= 1;
      // no fence, no flag, no second barrier
    }
  }
}

extern "C" void kernel_launch(void* const* d_in, const int* in_sizes, int n_in,
                              void* d_out, int out_size, void* d_ws, size_t ws_size,
                              hipStream_t stream) {
  (void)in_sizes; (void)n_in; (void)out_size; (void)ws_size;
  const float* x    = (const float*)d_in[0];
  const float* W0   = (const float*)d_in[1];
  const float* b0   = (const float*)d_in[2];
  const float* Wmid = (const float*)d_in[3];
  const float* bmid = (const float*)d_in[4];
  const float* Wf   = (const float*)d_in[5];
  const float* bfv  = (const float*)d_in[6];
  float* out = (float*)d_out;

  uint8_t* ws = (uint8_t*)d_ws;
  uint32_t* Hbuf = (uint32_t*)(ws + 0);
  uint32_t* bufA = (uint32_t*)(ws + 4096);
  uint32_t* bufB = (uint32_t*)(ws + 12288);

  // reset tags + hidden every call: {bf16 0.0, tag 0} == "H ready for t=0"
  hipMemsetAsync(d_ws, 0, 20480, stream);

  rnn_persist<<<dim3(NWG), dim3(256), 0, stream>>>(
      x, W0, b0, Wmid, bmid, Wf, bfv, out, Hbuf, bufA, bufB);
}